// Round 1
// baseline (28.537 us; speedup 1.0000x reference)
//
#include <hip/hip_runtime.h>

// Problem: B=128, x1/x2/x3 (B,2048,7,7) f32, W (14,2048), b (14,)
// softmax over singleton axis == 1.0 exactly  =>  h = 2*x1 + x2  (x3 unused!)
// feats[b,n] = mean_c(2*x1 + x2) ; logits = feats @ W^T + b
// Output: logits (128*14) then feats (128*2048), f32, concatenated flat.

#define NROWS (128 * 2048)   // 262144 rows of length 49
#define FC_B 128
#define FC_N 2048
#define FC_J 14

// 16 lanes per row, 16 rows per 256-thread block.
__global__ __launch_bounds__(256) void feats_kernel(const float* __restrict__ x1,
                                                    const float* __restrict__ x2,
                                                    float* __restrict__ feats) {
    const int tid = threadIdx.x;
    const int g = tid >> 4;       // row group within block (0..15)
    const int t = tid & 15;       // lane within row group
    const int r = blockIdx.x * 16 + g;
    if (r >= NROWS) return;

    const float* p1 = x1 + (size_t)r * 49;
    const float* p2 = x2 + (size_t)r * 49;

    // 49 = 16*3 + 1 : lanes cover [t, t+16, t+32], lane 0 picks up element 48
    float a = p1[t] + p1[t + 16] + p1[t + 32];
    float c = p2[t] + p2[t + 16] + p2[t + 32];
    if (t == 0) { a += p1[48]; c += p2[48]; }
    float v = 2.0f * a + c;

    // reduce across the 16-lane group
    #pragma unroll
    for (int m = 8; m >= 1; m >>= 1)
        v += __shfl_xor(v, m, 16);

    if (t == 0) feats[r] = v * (1.0f / 49.0f);
}

// One block per batch row b: logits[b,j] = bias[j] + sum_n feats[b,n]*W[j,n]
__global__ __launch_bounds__(256) void fc_kernel(const float* __restrict__ feats,
                                                 const float* __restrict__ W,
                                                 const float* __restrict__ bias,
                                                 float* __restrict__ logits) {
    const int b = blockIdx.x;
    const float* f = feats + (size_t)b * FC_N;

    float acc[FC_J];
    #pragma unroll
    for (int j = 0; j < FC_J; ++j) acc[j] = 0.0f;

    for (int n = threadIdx.x; n < FC_N; n += 256) {
        const float fv = f[n];
        #pragma unroll
        for (int j = 0; j < FC_J; ++j)
            acc[j] += fv * W[j * FC_N + n];
    }

    // wave-level reduce (wave = 64 lanes)
    #pragma unroll
    for (int j = 0; j < FC_J; ++j) {
        #pragma unroll
        for (int off = 32; off >= 1; off >>= 1)
            acc[j] += __shfl_xor(acc[j], off, 64);
    }

    __shared__ float part[4][FC_J];
    const int wid = threadIdx.x >> 6;
    const int lane = threadIdx.x & 63;
    if (lane == 0) {
        #pragma unroll
        for (int j = 0; j < FC_J; ++j) part[wid][j] = acc[j];
    }
    __syncthreads();

    if (threadIdx.x < FC_J) {
        const int j = threadIdx.x;
        float s = part[0][j] + part[1][j] + part[2][j] + part[3][j];
        logits[b * FC_J + j] = s + bias[j];
    }
}

extern "C" void kernel_launch(void* const* d_in, const int* in_sizes, int n_in,
                              void* d_out, int out_size, void* d_ws, size_t ws_size,
                              hipStream_t stream) {
    const float* x1 = (const float*)d_in[0];
    const float* x2 = (const float*)d_in[1];
    // d_in[2] = x3 — provably unused (softmax over singleton axis == 1)
    const float* W = (const float*)d_in[3];
    const float* bias = (const float*)d_in[4];

    float* out = (float*)d_out;
    float* logits = out;                 // 128*14 = 1792
    float* feats = out + FC_B * FC_J;    // 128*2048 = 262144

    feats_kernel<<<NROWS / 16, 256, 0, stream>>>(x1, x2, feats);
    fc_kernel<<<FC_B, 256, 0, stream>>>(feats, W, bias, logits);
}